// Round 7
// baseline (381.239 us; speedup 1.0000x reference)
//
#include <hip/hip_runtime.h>
#include <hip/hip_bf16.h>

#define HW    16384   // 128*128
#define IMW   128
#define IMH   128
#define CIN   256
#define CR    64
#define G     16
#define GC    16
#define M2    144     // K*K*G = dynamic-weight channels

typedef __attribute__((ext_vector_type(8))) short short8;
typedef __attribute__((ext_vector_type(4))) float floatx4;

static __device__ __forceinline__ short f2bf(float f) {
  union { float f; unsigned u; } v; v.f = f;
  unsigned r = v.u + 0x7fffu + ((v.u >> 16) & 1u);   // RNE
  return (short)(r >> 16);
}
static __device__ __forceinline__ float bf2f(short s) {
  union { unsigned u; float f; } v; v.u = ((unsigned)(unsigned short)s) << 16;
  return v.f;
}

#define GLL16(g, l) __builtin_amdgcn_global_load_lds( \
    (const __attribute__((address_space(1))) void*)(g), \
    (__attribute__((address_space(3))) void*)(l), 16, 0, 0)

// ---------------------------------------------------------------------------
// K0 (r3-verified): blocks 0..63: w1 fp32[64][256] -> bf16 w1b (overlapping
// y2b head — r3/r4/r5-verified trick). blocks 64..99: w2 fp32[144][64] ->
// bf16 main w2b + bf16 residual w2r (w2b + w2r ~= w2 to ~2^-17 rel;
// HW-verified in r3/r5: absmax unchanged).
// ---------------------------------------------------------------------------
__global__ __launch_bounds__(256) void k_cvt(const float* __restrict__ w1,
                                             const float* __restrict__ w2,
                                             short* __restrict__ w1b,
                                             short* __restrict__ w2b,
                                             short* __restrict__ w2r) {
  const int blk = blockIdx.x;
  if (blk < 64) {
    const int i = blk * 256 + threadIdx.x;           // 16384 elements
    w1b[i] = f2bf(w1[i]);
  } else {
    const int i = (blk - 64) * 256 + threadIdx.x;    // 9216 elements
    const float v = w2[i];
    const short hb = f2bf(v);
    w2b[i] = hb;
    w2r[i] = f2bf(v - bf2f(hb));
  }
}

// ---------------------------------------------------------------------------
// K1 (r6-verified): 1x1 conv 256->64 as bf16 MFMA GEMM, x staged through
// LDS via global_load_lds width=16. Block 256 = 4 waves; wave = 16 px x 64
// outputs. Grid 2048. LDS 8 KB.
// ---------------------------------------------------------------------------
__global__ __launch_bounds__(256) void k_conv1_mfma(const float* __restrict__ x,
                                                    const short* __restrict__ w1b,
                                                    const float* __restrict__ b1,
                                                    short* __restrict__ y1b) {
  __shared__ float xs[2048];            // [32 k][64 px] fp32, 8 KB
  const int blk  = blockIdx.x;          // b*256 + pixel-tile
  const int b    = blk >> 8;
  const int pt   = blk & 255;
  const int tid  = threadIdx.x;
  const int wave = tid >> 6;
  const int lane = tid & 63;
  const int quad = lane >> 4;
  const int l16  = lane & 15;
  const int px0  = pt * 64;
  const int p    = px0 + wave * 16 + l16;

  const float* xb = x + (size_t)b * CIN * HW + px0;
  const int krow = tid >> 4;            // 0..15
  const int scol = (tid & 15) * 4;      // 0..60

  floatx4 acc[4];
#pragma unroll
  for (int mt = 0; mt < 4; ++mt)
#pragma unroll
    for (int r = 0; r < 4; ++r) acc[mt][r] = b1[mt * 16 + quad * 4 + r];

#pragma unroll 1
  for (int kk = 0; kk < CIN; kk += 32) {
    GLL16(xb + (size_t)(kk + krow) * HW + scol,      xs + wave * 256);
    GLL16(xb + (size_t)(kk + 16 + krow) * HW + scol, xs + 1024 + wave * 256);
    __syncthreads();   // drains vmcnt -> whole [32][64] tile visible

    short8 af[4];
#pragma unroll
    for (int mt = 0; mt < 4; ++mt)
      af[mt] = *(const short8*)(w1b + (mt * 16 + l16) * CIN + kk + quad * 8);

    short8 bfrag;
#pragma unroll
    for (int j = 0; j < 8; ++j)
      bfrag[j] = f2bf(xs[(quad * 8 + j) * 64 + wave * 16 + l16]);

#pragma unroll
    for (int mt = 0; mt < 4; ++mt)
      acc[mt] = __builtin_amdgcn_mfma_f32_16x16x32_bf16(af[mt], bfrag, acc[mt], 0, 0, 0);
    __syncthreads();   // protect xs before next stage
  }

  short* yb = y1b + (size_t)b * CR * HW + p;
#pragma unroll
  for (int mt = 0; mt < 4; ++mt)
#pragma unroll
    for (int r = 0; r < 4; ++r)
      yb[(size_t)(mt * 16 + quad * 4 + r) * HW] = f2bf(acc[mt][r]);
}

// ---------------------------------------------------------------------------
// K2 (r1-verified, unchanged control): depthwise 3x3 over y1b (bf16),
// zero pad 1. Thread = 2 rows x 8 cols (short8). Grid 2048.
// ---------------------------------------------------------------------------
__global__ __launch_bounds__(256) void k_dw(const short* __restrict__ y1b,
                                            const float* __restrict__ wd,
                                            const float* __restrict__ bd,
                                            short* __restrict__ y2b) {
  const int blk   = blockIdx.x;         // ((b*64 + c)*4 + strip)
  const int strip = blk & 3;
  const int c     = (blk >> 2) & 63;
  const int b     = blk >> 8;
  const int tcol  = threadIdx.x & 15;
  const int trow  = threadIdx.x >> 4;
  const int r0    = strip * 32 + trow * 2;
  const int c0    = tcol * 8;

  const short* src = y1b + (size_t)(b * CR + c) * HW;

  const float mcl = c0 > 0 ? 1.f : 0.f;
  const float mcr = c0 + 8 < IMW ? 1.f : 0.f;
  const int   cl  = c0 > 0 ? c0 - 1 : 0;
  const int   crr = c0 + 8 < IMW ? c0 + 8 : IMW - 1;

  float f[4][10];
#pragma unroll
  for (int i = 0; i < 4; ++i) {
    const int rr = r0 - 1 + i;
    const int rc = rr < 0 ? 0 : (rr > IMH - 1 ? IMH - 1 : rr);
    const float mr = (rr < 0 || rr > IMH - 1) ? 0.f : 1.f;
    const short* row = src + rc * IMW;
    const short8 v = *(const short8*)(row + c0);
#pragma unroll
    for (int j = 0; j < 8; ++j) f[i][j + 1] = mr * bf2f(v[j]);
    f[i][0] = mr * mcl * bf2f(row[cl]);
    f[i][9] = mr * mcr * bf2f(row[crr]);
  }

  float wv[9];
#pragma unroll
  for (int j = 0; j < 9; ++j) wv[j] = wd[c * 9 + j];
  const float bias = bd[c];

  short* dst = y2b + (size_t)(b * CR + c) * HW + r0 * IMW + c0;
#pragma unroll
  for (int i = 0; i < 2; ++i) {
    short8 o;
#pragma unroll
    for (int xcol = 0; xcol < 8; ++xcol) {
      float acc = bias;
#pragma unroll
      for (int kh = 0; kh < 3; ++kh)
#pragma unroll
        for (int kw = 0; kw < 3; ++kw)
          acc += wv[kh * 3 + kw] * f[i + kh][xcol + kw];
      o[xcol] = f2bf(acc);
    }
    *(short8*)(dst + i * IMW) = o;
  }
}

// ---------------------------------------------------------------------------
// K3a (batches 0-3): dynamic-weight GEMM via MFMA: wdyn[144xHW] =
// (w2b + w2r)[144x64] * y2[64xHW] + b2, fp32 out. Same math as r5's
// HW-verified phase 1 (same accumulation order: main,res per K-step).
// wdyn lives in the out-buffer space of batches 4-7 (written later).
// Block 256 = 4 waves; wave = 16 px x 144 outputs (9 M-tiles, K = 2x32).
// Grid: 4 * 256 = 1024 blocks.
// ---------------------------------------------------------------------------
__global__ __launch_bounds__(256) void k_wgen(const short* __restrict__ y2b,
                                              const short* __restrict__ w2b,
                                              const short* __restrict__ w2r,
                                              const float* __restrict__ b2,
                                              float* __restrict__ wdyn) {
  const int blk  = blockIdx.x;          // b*256 + pixel-tile, b in 0..3
  const int b    = blk >> 8;
  const int pt   = blk & 255;
  const int wave = threadIdx.x >> 6;
  const int lane = threadIdx.x & 63;
  const int quad = lane >> 4;
  const int l16  = lane & 15;
  const int p    = pt * 64 + wave * 16 + l16;

  const short* y2p = y2b + (size_t)b * CR * HW + p;

  floatx4 acc[9];
#pragma unroll
  for (int mt = 0; mt < 9; ++mt)
#pragma unroll
    for (int r = 0; r < 4; ++r) acc[mt][r] = b2[mt * 16 + quad * 4 + r];

#pragma unroll
  for (int kk = 0; kk < CR; kk += 32) {
    short8 bfrag;
#pragma unroll
    for (int j = 0; j < 8; ++j)
      bfrag[j] = y2p[(size_t)(kk + quad * 8 + j) * HW];
#pragma unroll
    for (int mt = 0; mt < 9; ++mt) {
      const short8 af = *(const short8*)(w2b + (mt * 16 + l16) * CR + kk + quad * 8);
      acc[mt] = __builtin_amdgcn_mfma_f32_16x16x32_bf16(af, bfrag, acc[mt], 0, 0, 0);
    }
#pragma unroll
    for (int mt = 0; mt < 9; ++mt) {
      const short8 ar = *(const short8*)(w2r + (mt * 16 + l16) * CR + kk + quad * 8);
      acc[mt] = __builtin_amdgcn_mfma_f32_16x16x32_bf16(ar, bfrag, acc[mt], 0, 0, 0);
    }
  }

  float* wb = wdyn + (size_t)b * M2 * HW + p;
#pragma unroll
  for (int mt = 0; mt < 9; ++mt)
#pragma unroll
    for (int r = 0; r < 4; ++r)
      wb[(size_t)(mt * 16 + quad * 4 + r) * HW] = acc[mt][r];
}

// ---------------------------------------------------------------------------
// K3b (batches 0-3): pure streaming involution. Thread = 4 px x 1 group:
// 9 float4 wdyn loads (border zeroing == mask folding, bit-exact), then
// 16 channels x {3 float4 + 6 scalar x loads, 36 FMA, 1 float4 store}.
// Grid: 4 * 16 * 16 = 1024 blocks.
// ---------------------------------------------------------------------------
__global__ __launch_bounds__(256) void k_invol(const float* __restrict__ x,
                                               const float* __restrict__ wdyn,
                                               float* __restrict__ out) {
  const int blk  = blockIdx.x;          // ((b*16 + g)*16 + s), b in 0..3
  const int s    = blk & 15;
  const int g    = (blk >> 4) & 15;
  const int b    = blk >> 8;
  const int tcol = threadIdx.x & 31;
  const int trow = threadIdx.x >> 5;
  const int h    = s * 8 + trow;
  const int c0   = tcol * 4;
  const int p0   = h * IMW + c0;

  const float* wp = wdyn + ((size_t)b * M2 + (size_t)g * 9) * HW + p0;
  float wv[9][4];
#pragma unroll
  for (int j = 0; j < 9; ++j) {
    const float4 v = *(const float4*)(wp + (size_t)j * HW);
    wv[j][0] = v.x; wv[j][1] = v.y; wv[j][2] = v.z; wv[j][3] = v.w;
  }
  if (h == 0) {
#pragma unroll
    for (int j = 0; j < 3; ++j)
      wv[j][0] = wv[j][1] = wv[j][2] = wv[j][3] = 0.f;
  }
  if (h == IMH - 1) {
#pragma unroll
    for (int j = 6; j < 9; ++j)
      wv[j][0] = wv[j][1] = wv[j][2] = wv[j][3] = 0.f;
  }
  if (c0 == 0)       { wv[0][0] = wv[3][0] = wv[6][0] = 0.f; }
  if (c0 == IMW - 4) { wv[2][3] = wv[5][3] = wv[8][3] = 0.f; }

  const int r[3] = { (h > 0 ? h - 1 : 0) * IMW, h * IMW,
                     (h < IMH - 1 ? h + 1 : IMH - 1) * IMW };
  const int cl = c0 > 0 ? c0 - 1 : 0;
  const int cr = c0 + 4 < IMW ? c0 + 4 : IMW - 1;

  const float* xg = x   + ((size_t)b * CIN + (size_t)g * GC) * HW;
  float*       og = out + ((size_t)b * CIN + (size_t)g * GC) * HW;

#pragma unroll 2
  for (int cc = 0; cc < GC; ++cc) {
    const float* xp = xg + (size_t)cc * HW;
    float v[3][6];
#pragma unroll
    for (int rr = 0; rr < 3; ++rr) {
      const float4 m = *(const float4*)(xp + r[rr] + c0);
      v[rr][0] = xp[r[rr] + cl];
      v[rr][1] = m.x; v[rr][2] = m.y; v[rr][3] = m.z; v[rr][4] = m.w;
      v[rr][5] = xp[r[rr] + cr];
    }
    float o[4];
#pragma unroll
    for (int px = 0; px < 4; ++px) {
      float acc = 0.f;
#pragma unroll
      for (int kh = 0; kh < 3; ++kh)
#pragma unroll
        for (int kw = 0; kw < 3; ++kw)
          acc += wv[kh * 3 + kw][px] * v[kh][px + kw];
      o[px] = acc;
    }
    float4 ov; ov.x = o[0]; ov.y = o[1]; ov.z = o[2]; ov.w = o[3];
    *(float4*)(og + (size_t)cc * HW + p0) = ov;
  }
}

// ---------------------------------------------------------------------------
// K3c (batches 4-7, r1/r6-verified EXACT): fused conv2 + involution.
// 8x32 px tile, 2 groups/block, phase-1 unroll 2. Grid 2048. Runs AFTER
// k_invol has consumed wdyn (which aliases out[4-7] space) — stream order.
// ---------------------------------------------------------------------------
__global__ __launch_bounds__(256) void k_conv2invol(const float* __restrict__ x,
                                                    const short* __restrict__ y2b,
                                                    const float* __restrict__ w2,
                                                    const float* __restrict__ b2,
                                                    float* __restrict__ out) {
  const int blk  = blockIdx.x;         // (bb*8 + gp)*64 + tile, bb in 0..3
  const int tile = blk & 63;           // 16 row-tiles x 4 col-tiles
  const int gp   = (blk >> 6) & 7;
  const int b    = 4 + (blk >> 9);
  const int g0   = gp * 2;
  const int tid  = threadIdx.x;
  const int tr   = tid >> 5;           // 0..7
  const int tc   = tid & 31;           // 0..31
  const int h    = (tile >> 2) * 8 + tr;
  const int w    = (tile & 3) * 32 + tc;
  const int p    = h * IMW + w;

  float wv[2][9];
#pragma unroll
  for (int q = 0; q < 2; ++q)
#pragma unroll
    for (int j = 0; j < 9; ++j) wv[q][j] = b2[(g0 + q) * 9 + j];

  const short* y2p = y2b + (size_t)b * CR * HW + p;
#pragma unroll 2
  for (int c = 0; c < CR; c += 4) {
    const float v0 = bf2f(y2p[(size_t)(c + 0) * HW]);
    const float v1 = bf2f(y2p[(size_t)(c + 1) * HW]);
    const float v2 = bf2f(y2p[(size_t)(c + 2) * HW]);
    const float v3 = bf2f(y2p[(size_t)(c + 3) * HW]);
#pragma unroll
    for (int q = 0; q < 2; ++q)
#pragma unroll
      for (int j = 0; j < 9; ++j) {
        const float4 wq = *(const float4*)(w2 + ((g0 + q) * 9 + j) * CR + c); // uniform
        wv[q][j] += wq.x * v0 + wq.y * v1 + wq.z * v2 + wq.w * v3;
      }
  }

  const int   hcl[3] = {h > 0 ? h - 1 : 0, h, h < IMH - 1 ? h + 1 : IMH - 1};
  const int   wcl[3] = {w > 0 ? w - 1 : 0, w, w < IMW - 1 ? w + 1 : IMW - 1};
  const float mr[3]  = {h > 0 ? 1.f : 0.f, 1.f, h < IMH - 1 ? 1.f : 0.f};
  const float mc[3]  = {w > 0 ? 1.f : 0.f, 1.f, w < IMW - 1 ? 1.f : 0.f};
  int rel[9];
#pragma unroll
  for (int kh = 0; kh < 3; ++kh)
#pragma unroll
    for (int kw = 0; kw < 3; ++kw) {
      rel[kh * 3 + kw] = hcl[kh] * IMW + wcl[kw];
      const float m = mr[kh] * mc[kw];
      wv[0][kh * 3 + kw] *= m;
      wv[1][kh * 3 + kw] *= m;
    }

  const float* xb = x + (size_t)b * CIN * HW;
  float*       ob = out + (size_t)b * CIN * HW;

#pragma unroll
  for (int q = 0; q < 2; ++q) {
#pragma unroll 4
    for (int cc = 0; cc < GC; ++cc) {
      const int ch = (g0 + q) * GC + cc;
      const float* xp = xb + (size_t)ch * HW;
      float acc = 0.f;
#pragma unroll
      for (int j = 0; j < 9; ++j) acc += wv[q][j] * xp[rel[j]];
      ob[(size_t)ch * HW + p] = acc;
    }
  }
}

extern "C" void kernel_launch(void* const* d_in, const int* in_sizes, int n_in,
                              void* d_out, int out_size, void* d_ws, size_t ws_size,
                              hipStream_t stream) {
  const float* x  = (const float*)d_in[0];
  const float* w1 = (const float*)d_in[1];
  const float* b1 = (const float*)d_in[2];
  const float* wd = (const float*)d_in[3];
  const float* bd = (const float*)d_in[4];
  const float* w2 = (const float*)d_in[5];
  const float* b2 = (const float*)d_in[6];
  float* out = (float*)d_out;

  // ws layout (33.62 MB, r5-verified):
  //   0        : w2b bf16 18 KB
  //   18432    : w2r bf16 18 KB      (gap to 64 KB unused)
  //   65536    : y1b bf16 16.78 MB   (dead after k_dw)
  //   16842752 : y2b bf16 16.78 MB
  //   w1b bf16 32 KB OVERLAPS the start of y2b (r3/r4/r5-verified): written
  //   by k_cvt, read by k_conv1, then overwritten by k_dw's y2b stores.
  short* w2b = (short*)d_ws;
  short* w2r = (short*)((char*)d_ws + 18432);
  short* y1b = (short*)((char*)d_ws + 65536);
  short* y2b = (short*)((char*)d_ws + 65536 + 16777216);
  short* w1b = y2b;

  // wdyn (fp32 [4][144][HW] = 37.75 MB) lives in out-space of batches 4-7
  // (67.1 MB), which k_conv2invol overwrites only AFTER k_invol consumed it.
  float* wdyn = out + (size_t)4 * CIN * HW;

  k_cvt<<<dim3(100), dim3(256), 0, stream>>>(w1, w2, w1b, w2b, w2r);
  k_conv1_mfma<<<dim3(2048), dim3(256), 0, stream>>>(x, w1b, b1, y1b);
  k_dw<<<dim3(2048), dim3(256), 0, stream>>>(y1b, wd, bd, y2b);
  k_wgen<<<dim3(1024), dim3(256), 0, stream>>>(y2b, w2b, w2r, b2, wdyn);
  k_invol<<<dim3(1024), dim3(256), 0, stream>>>(x, wdyn, out);
  k_conv2invol<<<dim3(2048), dim3(256), 0, stream>>>(x, y2b, w2, b2, out);
}

// Round 8
// 353.717 us; speedup vs baseline: 1.0778x; 1.0778x over previous
//
#include <hip/hip_runtime.h>
#include <hip/hip_bf16.h>

#define HW    16384   // 128*128
#define IMW   128
#define IMH   128
#define CIN   256
#define CR    64
#define G     16
#define GC    16

typedef __attribute__((ext_vector_type(8))) short short8;
typedef __attribute__((ext_vector_type(4))) float floatx4;

static __device__ __forceinline__ short f2bf(float f) {
  union { float f; unsigned u; } v; v.f = f;
  unsigned r = v.u + 0x7fffu + ((v.u >> 16) & 1u);   // RNE
  return (short)(r >> 16);
}
static __device__ __forceinline__ float bf2f(short s) {
  union { unsigned u; float f; } v; v.u = ((unsigned)(unsigned short)s) << 16;
  return v.f;
}

#define GLL16(g, l) __builtin_amdgcn_global_load_lds( \
    (const __attribute__((address_space(1))) void*)(g), \
    (__attribute__((address_space(3))) void*)(l), 16, 0, 0)

// ---------------------------------------------------------------------------
// K0 (round-0 verified): convert w1 (fp32 [64][256]) -> bf16. 64 blocks.
// ---------------------------------------------------------------------------
__global__ __launch_bounds__(256) void k_cvt_w1(const float* __restrict__ w1,
                                                short* __restrict__ w1b) {
  const int i = blockIdx.x * 256 + threadIdx.x;      // 16384 elements
  w1b[i] = f2bf(w1[i]);
}

// ---------------------------------------------------------------------------
// K1 (r6-verified): 1x1 conv 256->64 as bf16 MFMA GEMM, x staged through
// LDS via global_load_lds width=16. Block 256 = 4 waves; wave = 16 px x 64
// outputs. Grid 2048. LDS 8 KB.
// ---------------------------------------------------------------------------
__global__ __launch_bounds__(256) void k_conv1_mfma(const float* __restrict__ x,
                                                    const short* __restrict__ w1b,
                                                    const float* __restrict__ b1,
                                                    short* __restrict__ y1b) {
  __shared__ float xs[2048];            // [32 k][64 px] fp32, 8 KB
  const int blk  = blockIdx.x;          // b*256 + pixel-tile
  const int b    = blk >> 8;
  const int pt   = blk & 255;
  const int tid  = threadIdx.x;
  const int wave = tid >> 6;
  const int lane = tid & 63;
  const int quad = lane >> 4;
  const int l16  = lane & 15;
  const int px0  = pt * 64;
  const int p    = px0 + wave * 16 + l16;

  const float* xb = x + (size_t)b * CIN * HW + px0;
  const int krow = tid >> 4;            // 0..15
  const int scol = (tid & 15) * 4;      // 0..60

  floatx4 acc[4];
#pragma unroll
  for (int mt = 0; mt < 4; ++mt)
#pragma unroll
    for (int r = 0; r < 4; ++r) acc[mt][r] = b1[mt * 16 + quad * 4 + r];

#pragma unroll 1
  for (int kk = 0; kk < CIN; kk += 32) {
    GLL16(xb + (size_t)(kk + krow) * HW + scol,      xs + wave * 256);
    GLL16(xb + (size_t)(kk + 16 + krow) * HW + scol, xs + 1024 + wave * 256);
    __syncthreads();   // drains vmcnt -> whole [32][64] tile visible

    short8 af[4];
#pragma unroll
    for (int mt = 0; mt < 4; ++mt)
      af[mt] = *(const short8*)(w1b + (mt * 16 + l16) * CIN + kk + quad * 8);

    short8 bfrag;
#pragma unroll
    for (int j = 0; j < 8; ++j)
      bfrag[j] = f2bf(xs[(quad * 8 + j) * 64 + wave * 16 + l16]);

#pragma unroll
    for (int mt = 0; mt < 4; ++mt)
      acc[mt] = __builtin_amdgcn_mfma_f32_16x16x32_bf16(af[mt], bfrag, acc[mt], 0, 0, 0);
    __syncthreads();   // protect xs before next stage
  }

  short* yb = y1b + (size_t)b * CR * HW + p;
#pragma unroll
  for (int mt = 0; mt < 4; ++mt)
#pragma unroll
    for (int r = 0; r < 4; ++r)
      yb[(size_t)(mt * 16 + quad * 4 + r) * HW] = f2bf(acc[mt][r]);
}

// ---------------------------------------------------------------------------
// K2 (r1-verified, unchanged control): depthwise 3x3 over y1b (bf16),
// zero pad 1. Thread = 2 rows x 8 cols (short8). Grid 2048.
// ---------------------------------------------------------------------------
__global__ __launch_bounds__(256) void k_dw(const short* __restrict__ y1b,
                                            const float* __restrict__ wd,
                                            const float* __restrict__ bd,
                                            short* __restrict__ y2b) {
  const int blk   = blockIdx.x;         // ((b*64 + c)*4 + strip)
  const int strip = blk & 3;
  const int c     = (blk >> 2) & 63;
  const int b     = blk >> 8;
  const int tcol  = threadIdx.x & 15;
  const int trow  = threadIdx.x >> 4;
  const int r0    = strip * 32 + trow * 2;
  const int c0    = tcol * 8;

  const short* src = y1b + (size_t)(b * CR + c) * HW;

  const float mcl = c0 > 0 ? 1.f : 0.f;
  const float mcr = c0 + 8 < IMW ? 1.f : 0.f;
  const int   cl  = c0 > 0 ? c0 - 1 : 0;
  const int   crr = c0 + 8 < IMW ? c0 + 8 : IMW - 1;

  float f[4][10];
#pragma unroll
  for (int i = 0; i < 4; ++i) {
    const int rr = r0 - 1 + i;
    const int rc = rr < 0 ? 0 : (rr > IMH - 1 ? IMH - 1 : rr);
    const float mr = (rr < 0 || rr > IMH - 1) ? 0.f : 1.f;
    const short* row = src + rc * IMW;
    const short8 v = *(const short8*)(row + c0);
#pragma unroll
    for (int j = 0; j < 8; ++j) f[i][j + 1] = mr * bf2f(v[j]);
    f[i][0] = mr * mcl * bf2f(row[cl]);
    f[i][9] = mr * mcr * bf2f(row[crr]);
  }

  float wv[9];
#pragma unroll
  for (int j = 0; j < 9; ++j) wv[j] = wd[c * 9 + j];
  const float bias = bd[c];

  short* dst = y2b + (size_t)(b * CR + c) * HW + r0 * IMW + c0;
#pragma unroll
  for (int i = 0; i < 2; ++i) {
    short8 o;
#pragma unroll
    for (int xcol = 0; xcol < 8; ++xcol) {
      float acc = bias;
#pragma unroll
      for (int kh = 0; kh < 3; ++kh)
#pragma unroll
        for (int kw = 0; kw < 3; ++kw)
          acc += wv[kh * 3 + kw] * f[i + kh][xcol + kw];
      o[xcol] = f2bf(acc);
    }
    *(short8*)(dst + i * IMW) = o;
  }
}

// ---------------------------------------------------------------------------
// K3 (r1/r6-verified structure + NEW XCD swizzle): fused conv2 + involution.
// 8x32 px tile, 2 groups/block, phase-1 unroll 2, no LDS. Grid 4096.
//
// XCD swizzle (T1): raw blockIdx round-robins XCDs (xcd = bid % 8), so the
// 512 blocks sharing batch b's y2 plane (2.1 MB) were spread over all 8
// private L2s -> y2 fetched 8x from HBM (134 MB of the 223 MB FETCH).
// wgid = (bid&7)*512 + (bid>>3) is bijective (4096 % 8 == 0) and pins all
// of batch k's blocks to XCD k -> y2[b] L2-resident, read once (~17 MB).
// Pure index remap — numerics identical.
// ---------------------------------------------------------------------------
__global__ __launch_bounds__(256) void k_conv2invol(const float* __restrict__ x,
                                                    const short* __restrict__ y2b,
                                                    const float* __restrict__ w2,
                                                    const float* __restrict__ b2,
                                                    float* __restrict__ out) {
  const int bid  = blockIdx.x;
  const int blk  = (bid & 7) * 512 + (bid >> 3);   // XCD-aware bijection
  const int tile = blk & 63;           // 16 row-tiles x 4 col-tiles
  const int gp   = (blk >> 6) & 7;
  const int b    = blk >> 9;
  const int g0   = gp * 2;
  const int tid  = threadIdx.x;
  const int tr   = tid >> 5;           // 0..7
  const int tc   = tid & 31;           // 0..31
  const int h    = (tile >> 2) * 8 + tr;
  const int w    = (tile & 3) * 32 + tc;
  const int p    = h * IMW + w;

  // ---- phase 1: dynamic weights for this pixel, groups g0, g0+1 ----
  float wv[2][9];
#pragma unroll
  for (int q = 0; q < 2; ++q)
#pragma unroll
    for (int j = 0; j < 9; ++j) wv[q][j] = b2[(g0 + q) * 9 + j];

  const short* y2p = y2b + (size_t)b * CR * HW + p;
#pragma unroll 2
  for (int c = 0; c < CR; c += 4) {
    const float v0 = bf2f(y2p[(size_t)(c + 0) * HW]);
    const float v1 = bf2f(y2p[(size_t)(c + 1) * HW]);
    const float v2 = bf2f(y2p[(size_t)(c + 2) * HW]);
    const float v3 = bf2f(y2p[(size_t)(c + 3) * HW]);
#pragma unroll
    for (int q = 0; q < 2; ++q)
#pragma unroll
      for (int j = 0; j < 9; ++j) {
        const float4 wq = *(const float4*)(w2 + ((g0 + q) * 9 + j) * CR + c); // uniform
        wv[q][j] += wq.x * v0 + wq.y * v1 + wq.z * v2 + wq.w * v3;
      }
  }

  // ---- fold borders into weights; clamped tap offsets ----
  const int   hcl[3] = {h > 0 ? h - 1 : 0, h, h < IMH - 1 ? h + 1 : IMH - 1};
  const int   wcl[3] = {w > 0 ? w - 1 : 0, w, w < IMW - 1 ? w + 1 : IMW - 1};
  const float mr[3]  = {h > 0 ? 1.f : 0.f, 1.f, h < IMH - 1 ? 1.f : 0.f};
  const float mc[3]  = {w > 0 ? 1.f : 0.f, 1.f, w < IMW - 1 ? 1.f : 0.f};
  int rel[9];
#pragma unroll
  for (int kh = 0; kh < 3; ++kh)
#pragma unroll
    for (int kw = 0; kw < 3; ++kw) {
      rel[kh * 3 + kw] = hcl[kh] * IMW + wcl[kw];
      const float m = mr[kh] * mc[kw];
      wv[0][kh * 3 + kw] *= m;
      wv[1][kh * 3 + kw] *= m;
    }

  // ---- phase 2: involution, branchless taps through L1 ----
  const float* xb = x + (size_t)b * CIN * HW;
  float*       ob = out + (size_t)b * CIN * HW;

#pragma unroll
  for (int q = 0; q < 2; ++q) {
#pragma unroll 4
    for (int cc = 0; cc < GC; ++cc) {
      const int ch = (g0 + q) * GC + cc;
      const float* xp = xb + (size_t)ch * HW;
      float acc = 0.f;
#pragma unroll
      for (int j = 0; j < 9; ++j) acc += wv[q][j] * xp[rel[j]];
      ob[(size_t)ch * HW + p] = acc;
    }
  }
}

extern "C" void kernel_launch(void* const* d_in, const int* in_sizes, int n_in,
                              void* d_out, int out_size, void* d_ws, size_t ws_size,
                              hipStream_t stream) {
  const float* x  = (const float*)d_in[0];
  const float* w1 = (const float*)d_in[1];
  const float* b1 = (const float*)d_in[2];
  const float* wd = (const float*)d_in[3];
  const float* bd = (const float*)d_in[4];
  const float* w2 = (const float*)d_in[5];
  const float* b2 = (const float*)d_in[6];
  float* out = (float*)d_out;

  // ws layout (33.62 MB, r6-verified):
  //   w1b bf16 (32 KB, padded to 64 KB) | y1b bf16 16.78 MB | y2b bf16 16.78 MB
  short* w1b = (short*)d_ws;
  short* y1b = (short*)((char*)d_ws + 65536);
  short* y2b = y1b + (size_t)8 * CR * HW;

  k_cvt_w1<<<dim3(64), dim3(256), 0, stream>>>(w1, w1b);
  k_conv1_mfma<<<dim3(2048), dim3(256), 0, stream>>>(x, w1b, b1, y1b);
  k_dw<<<dim3(2048), dim3(256), 0, stream>>>(y1b, wd, bd, y2b);
  k_conv2invol<<<dim3(4096), dim3(256), 0, stream>>>(x, y2b, w2, b2, out);
}